// Round 3
// baseline (1284.710 us; speedup 1.0000x reference)
//
#include <hip/hip_runtime.h>

// CausalAttention: B=4, S=4096, D_IN=D_OUT=1024, fp32 in/out, bf16 MFMA compute.
//
// R3: k_attn redesigned for register fit (R2 spilled: WRITE_SIZE 372 MB vs 65 MB
// in R1 = scratch traffic). 16 waves/block, 1 block/CU, <=128 VGPR by
// construction: QK D-slice 64/wave (16 LDS partial copies), PV 64 cols/wave.
// Loads placed per-span so the vmcnt(0) barrier drain happens after a full
// span of cover. LDS-transposed epilogue for 128B-contiguous output stores.
//
// Fragment layouts (HW-verified, learn_hip m89/m91/m120):
//   A[m = lane&15][k = (lane>>4)*8 + j]
//   B[k = (lane>>4)*8 + j][n = lane&15]
//   D[row = (lane>>4)*4 + r][col = lane&15]

typedef __attribute__((ext_vector_type(8))) short bh8;
typedef __attribute__((ext_vector_type(4))) float f32x4;
typedef __attribute__((ext_vector_type(4))) unsigned int u32x4;

#define BATCH 4
#define SEQ   4096
#define DIM   1024
#define MTOT  (BATCH * SEQ)   // 16384

__device__ __forceinline__ unsigned short f2bf(float f) {
  union { float f; unsigned int u; } v; v.f = f;
  return (unsigned short)((v.u + 0x7FFFu + ((v.u >> 16) & 1u)) >> 16);  // RNE
}

// ---------------- kernel 1: x fp32 -> bf16 ----------------
__global__ __launch_bounds__(256)
void k_convert_x(const float* __restrict__ x, unsigned short* __restrict__ xb) {
  size_t idx = ((size_t)blockIdx.x * 256 + threadIdx.x) * 8;
  f32x4 v0 = *(const f32x4*)(x + idx);
  f32x4 v1 = *(const f32x4*)(x + idx + 4);
  u32x4 pk;
  pk[0] = (unsigned)f2bf(v0[0]) | ((unsigned)f2bf(v0[1]) << 16);
  pk[1] = (unsigned)f2bf(v0[2]) | ((unsigned)f2bf(v0[3]) << 16);
  pk[2] = (unsigned)f2bf(v1[0]) | ((unsigned)f2bf(v1[1]) << 16);
  pk[3] = (unsigned)f2bf(v1[2]) | ((unsigned)f2bf(v1[3]) << 16);
  *(u32x4*)(xb + idx) = pk;
}

// ---------------- kernel 2: W[k][n] fp32 -> Wt[n][k] bf16 (x3) ----------------
__global__ __launch_bounds__(256)
void k_transpose_w(const float* __restrict__ Wq, const float* __restrict__ Wk,
                   const float* __restrict__ Wv, unsigned short* __restrict__ wt) {
  __shared__ float tile[32][33];
  const int z = blockIdx.z;
  const float* W = (z == 0) ? Wq : ((z == 1) ? Wk : Wv);
  unsigned short* out = wt + (size_t)z * DIM * DIM;
  const int tx = threadIdx.x, ty = threadIdx.y;
  const int n = blockIdx.x * 32 + tx;
  const int k = blockIdx.y * 32 + ty;
#pragma unroll
  for (int i = 0; i < 32; i += 8)
    tile[ty + i][tx] = W[(size_t)(k + i) * DIM + n];
  __syncthreads();
  const int k2 = blockIdx.y * 32 + tx;
  const int n2 = blockIdx.x * 32 + ty;
#pragma unroll
  for (int i = 0; i < 32; i += 8)
    out[(size_t)(n2 + i) * DIM + k2] = f2bf(tile[tx][ty + i]);
}

// ---------------- kernel 3: QKV GEMM ----------------
// C[16384,1024] = xb @ W   (z=0 -> qb, z=1 -> kb, z=2 -> vt transposed [b][d][s])
__global__ __launch_bounds__(256)
void k_qkv_gemm(const unsigned short* __restrict__ xb, const unsigned short* __restrict__ wt,
                unsigned short* __restrict__ qb, unsigned short* __restrict__ kb,
                unsigned short* __restrict__ vt) {
  const int tid = threadIdx.x;
  const int l = tid & 63, w = tid >> 6;
  const int lane16 = l & 15, quad = l >> 4;
  const int wm = w & 1, wn = w >> 1;
  const int m0 = blockIdx.x * 128, n0 = blockIdx.y * 128, z = blockIdx.z;
  const unsigned short* wtz = wt + (size_t)z * DIM * DIM;

  __shared__ unsigned short As[128][40];
  __shared__ unsigned short Bs[128][40];

  f32x4 acc[4][4];
#pragma unroll
  for (int i = 0; i < 4; ++i)
#pragma unroll
    for (int j = 0; j < 4; ++j) acc[i][j] = (f32x4){0.f, 0.f, 0.f, 0.f};

  for (int k0 = 0; k0 < DIM; k0 += 32) {
#pragma unroll
    for (int i = 0; i < 2; ++i) {
      int c = tid + i * 256;
      int row = c >> 2, cc = (c & 3) * 8;
      *(bh8*)&As[row][cc] = *(const bh8*)(xb  + (size_t)(m0 + row) * DIM + k0 + cc);
      *(bh8*)&Bs[row][cc] = *(const bh8*)(wtz + (size_t)(n0 + row) * DIM + k0 + cc);
    }
    __syncthreads();
    bh8 a[4], b[4];
#pragma unroll
    for (int mt = 0; mt < 4; ++mt) a[mt] = *(const bh8*)&As[wm * 64 + mt * 16 + lane16][quad * 8];
#pragma unroll
    for (int nt = 0; nt < 4; ++nt) b[nt] = *(const bh8*)&Bs[wn * 64 + nt * 16 + lane16][quad * 8];
#pragma unroll
    for (int mt = 0; mt < 4; ++mt)
#pragma unroll
      for (int nt = 0; nt < 4; ++nt)
        acc[mt][nt] = __builtin_amdgcn_mfma_f32_16x16x32_bf16(a[mt], b[nt], acc[mt][nt], 0, 0, 0);
    __syncthreads();
  }

  if (z < 2) {
    unsigned short* outp = (z == 0) ? qb : kb;
#pragma unroll
    for (int mt = 0; mt < 4; ++mt)
#pragma unroll
      for (int nt = 0; nt < 4; ++nt) {
        int row = m0 + wm * 64 + mt * 16 + quad * 4;
        int col = n0 + wn * 64 + nt * 16 + lane16;
#pragma unroll
        for (int r = 0; r < 4; ++r)
          outp[(size_t)(row + r) * DIM + col] = f2bf(acc[mt][nt][r]);
      }
  } else {
#pragma unroll
    for (int mt = 0; mt < 4; ++mt)
#pragma unroll
      for (int nt = 0; nt < 4; ++nt) {
        int m = m0 + wm * 64 + mt * 16 + quad * 4;
        int bb = m >> 12, s = m & (SEQ - 1);
        int col = n0 + wn * 64 + nt * 16 + lane16;
        unsigned long long pk =
            (unsigned long long)f2bf(acc[mt][nt][0]) |
            ((unsigned long long)f2bf(acc[mt][nt][1]) << 16) |
            ((unsigned long long)f2bf(acc[mt][nt][2]) << 32) |
            ((unsigned long long)f2bf(acc[mt][nt][3]) << 48);
        *(unsigned long long*)(vt + (size_t)bb * DIM * SEQ + (size_t)col * SEQ + s) = pk;
      }
  }
}

// ---------------- kernel 4: causal flash attention (v3) ----------------
// 1024 threads = 16 waves, 1 block/CU, <=128 VGPR/wave by design.
// QK: wave w -> D-slice [w*64,+64), TK=32, writes its own Pp copy (no atomics).
// softmax: 1 cell/thread, 16-copy sum, 32-lane shuffle reduce.
// PV: wave w -> output cols [w*64,+64), o = 2x4 f32x4 (AGPR).
__global__ __launch_bounds__(1024)
void k_attn(const unsigned short* __restrict__ qb, const unsigned short* __restrict__ kb,
            const unsigned short* __restrict__ vt, float* __restrict__ out) {
  const int tid = threadIdx.x;
  const int w = tid >> 6;          // 0..15
  const int l = tid & 63;
  const int lane16 = l & 15, quad = l >> 4;
  const int batch = blockIdx.x;    // fast dim -> XCD affinity per batch
  const int pid = blockIdx.y;      // 0..63
  const int sr = tid >> 5;         // softmax row 0..31
  const int sc = tid & 31;         // softmax col 0..31

  __shared__ float Pp[16][32][36];          // 73.7 KB partial scores (16 copies)
  __shared__ unsigned short Psh[32][36];    // P bf16 for PV A-frags
  __shared__ float row_m[32], row_l[32], row_alpha[32];
  float* Oe = (float*)Pp;                   // epilogue alias (Pp dead then)

  const size_t bbase = (size_t)batch * SEQ;
  const unsigned short* vtb = vt + (size_t)batch * DIM * SEQ;
  const float cexp = 0.04508422002778f;     // log2(e)/sqrt(1024)

  for (int half = 0; half < 2; ++half) {
    const int t = half ? (127 - pid) : pid;
    const int q0 = t * 32;
    const int nk = t + 1;                   // TK=32 iterations

    // Q fragments: this wave's 64-dim slice, 2 row-blocks (16 regs, held)
    bh8 qf[2][2];
#pragma unroll
    for (int mt = 0; mt < 2; ++mt)
#pragma unroll
      for (int c = 0; c < 2; ++c)
        qf[mt][c] = *(const bh8*)(qb + (bbase + q0 + mt * 16 + lane16) * DIM +
                                  w * 64 + c * 32 + quad * 8);

    f32x4 o[2][4];
#pragma unroll
    for (int mt = 0; mt < 2; ++mt)
#pragma unroll
      for (int nt = 0; nt < 4; ++nt) o[mt][nt] = (f32x4){0.f, 0.f, 0.f, 0.f};

    bh8 kfA[2][2], kfB[2][2], vf[4], pf[2];
    // K(0)
#pragma unroll
    for (int kt = 0; kt < 2; ++kt)
#pragma unroll
      for (int c = 0; c < 2; ++c)
        kfA[kt][c] = *(const bh8*)(kb + (bbase + kt * 16 + lane16) * DIM +
                                   w * 64 + c * 32 + quad * 8);

    for (int it = 0; it < nk; ++it) {
      const int k0 = it * 32;

      // issue K(it+1) at span top: drains at barrier1 after PV+QK cover
      if (it + 1 < nk) {
#pragma unroll
        for (int kt = 0; kt < 2; ++kt)
#pragma unroll
          for (int c = 0; c < 2; ++c)
            kfB[kt][c] = *(const bh8*)(kb + (bbase + k0 + 32 + kt * 16 + lane16) * DIM +
                                       w * 64 + c * 32 + quad * 8);
      }

      // PV(it-1): rescale by alpha, then P @ V
      if (it > 0) {
        f32x4 al0, al1;
#pragma unroll
        for (int r = 0; r < 4; ++r) {
          al0[r] = row_alpha[quad * 4 + r];
          al1[r] = row_alpha[16 + quad * 4 + r];
        }
#pragma unroll
        for (int nt = 0; nt < 4; ++nt) { o[0][nt] *= al0; o[1][nt] *= al1; }
#pragma unroll
        for (int nt = 0; nt < 4; ++nt)
#pragma unroll
          for (int mt = 0; mt < 2; ++mt)
            o[mt][nt] = __builtin_amdgcn_mfma_f32_16x16x32_bf16(pf[mt], vf[nt], o[mt][nt], 0, 0, 0);
      }

      // QK(it): 32x32 scores over this wave's 64 dims -> own Pp copy
#pragma unroll
      for (int mt = 0; mt < 2; ++mt)
#pragma unroll
        for (int kt = 0; kt < 2; ++kt) {
          f32x4 s = (f32x4){0.f, 0.f, 0.f, 0.f};
          s = __builtin_amdgcn_mfma_f32_16x16x32_bf16(qf[mt][0], kfA[kt][0], s, 0, 0, 0);
          s = __builtin_amdgcn_mfma_f32_16x16x32_bf16(qf[mt][1], kfA[kt][1], s, 0, 0, 0);
          int row = mt * 16 + quad * 4;
          int col = kt * 16 + lane16;
#pragma unroll
          for (int r = 0; r < 4; ++r)
            Pp[w][row + r][col] = s[r];
        }
      __syncthreads();  // barrier1: partials visible

      // issue V(it): drains at barrier2 after softmax cover; used in next span
#pragma unroll
      for (int nt = 0; nt < 4; ++nt)
        vf[nt] = *(const bh8*)(vtb + (size_t)(w * 64 + nt * 16 + lane16) * SEQ +
                               k0 + quad * 8);

      // softmax: one cell per thread
      {
        float sv = Pp[0][sr][sc];
#pragma unroll
        for (int k = 1; k < 16; ++k) sv += Pp[k][sr][sc];
        if (k0 + sc > q0 + sr) sv = -3.0e38f;
        float mx = sv;
#pragma unroll
        for (int off = 1; off < 32; off <<= 1)
          mx = fmaxf(mx, __shfl_xor(mx, off));
        float mold = it ? row_m[sr] : -3.0e38f;
        float mnew = fmaxf(mold, mx);
        float p = __builtin_amdgcn_exp2f((sv - mnew) * cexp);
        float sum = p;
#pragma unroll
        for (int off = 1; off < 32; off <<= 1)
          sum += __shfl_xor(sum, off);
        float alpha = __builtin_amdgcn_exp2f((mold - mnew) * cexp);
        Psh[sr][sc] = f2bf(p);
        if (sc == 0) {
          row_m[sr] = mnew;
          row_l[sr] = alpha * (it ? row_l[sr] : 0.f) + sum;
          row_alpha[sr] = alpha;
        }
      }
      __syncthreads();  // barrier2: Psh / row state visible

      // P fragments for PV (A-layout)
      pf[0] = *(const bh8*)&Psh[lane16][quad * 8];
      pf[1] = *(const bh8*)&Psh[16 + lane16][quad * 8];

      // rotate K double-buffer
      if (it + 1 < nk) {
#pragma unroll
        for (int kt = 0; kt < 2; ++kt)
#pragma unroll
          for (int c = 0; c < 2; ++c) kfA[kt][c] = kfB[kt][c];
      }
    }

    // tail PV(nk-1)
    {
      f32x4 al0, al1;
#pragma unroll
      for (int r = 0; r < 4; ++r) {
        al0[r] = row_alpha[quad * 4 + r];
        al1[r] = row_alpha[16 + quad * 4 + r];
      }
#pragma unroll
      for (int nt = 0; nt < 4; ++nt) { o[0][nt] *= al0; o[1][nt] *= al1; }
#pragma unroll
      for (int nt = 0; nt < 4; ++nt)
#pragma unroll
        for (int mt = 0; mt < 2; ++mt)
          o[mt][nt] = __builtin_amdgcn_mfma_f32_16x16x32_bf16(pf[mt], vf[nt], o[mt][nt], 0, 0, 0);
    }

    // epilogue: divide by l, LDS-transpose (wave-local, reuses dead Pp),
    // then 128B-contiguous fp32 stores.
    {
      float* Ow = Oe + w * 1040;  // 16 rows x 65 floats per wave
#pragma unroll
      for (int mt = 0; mt < 2; ++mt) {
        float il[4];
#pragma unroll
        for (int r = 0; r < 4; ++r) il[r] = 1.0f / row_l[mt * 16 + quad * 4 + r];
#pragma unroll
        for (int nt = 0; nt < 4; ++nt)
#pragma unroll
          for (int r = 0; r < 4; ++r)
            Ow[(quad * 4 + r) * 65 + nt * 16 + lane16] = o[mt][nt][r] * il[r];
        // same-wave LDS RAW: compiler inserts lgkmcnt wait
        int row8 = l >> 3, c8 = l & 7;
#pragma unroll
        for (int set = 0; set < 2; ++set)
#pragma unroll
          for (int rep = 0; rep < 2; ++rep) {
            f32x4 v = *(const f32x4*)&Ow[(set * 8 + row8) * 65 + c8 * 4 + rep * 32];
            *(f32x4*)(out + (bbase + q0 + mt * 16 + set * 8 + row8) * DIM +
                      w * 64 + c8 * 4 + rep * 32) = v;
          }
      }
    }
    __syncthreads();  // Pp/row state reused by next tile
  }
}

// ---------------- launch ----------------
extern "C" void kernel_launch(void* const* d_in, const int* in_sizes, int n_in,
                              void* d_out, int out_size, void* d_ws, size_t ws_size,
                              hipStream_t stream) {
  const float* x  = (const float*)d_in[0];
  const float* Wq = (const float*)d_in[1];
  const float* Wk = (const float*)d_in[2];
  const float* Wv = (const float*)d_in[3];
  float* out = (float*)d_out;

  char* ws = (char*)d_ws;
  const size_t XB_BYTES = (size_t)MTOT * DIM * 2;        // 32 MB
  const size_t WT_BYTES = (size_t)3 * DIM * DIM * 2;     // 6 MB
  unsigned short* xb = (unsigned short*)(ws);
  unsigned short* wt = (unsigned short*)(ws + XB_BYTES);
  unsigned short* qb = (unsigned short*)(ws + XB_BYTES + WT_BYTES);
  unsigned short* kb = qb + (size_t)MTOT * DIM;
  unsigned short* vt = kb + (size_t)MTOT * DIM;

  k_convert_x<<<dim3((MTOT * DIM) / (256 * 8)), dim3(256), 0, stream>>>(x, xb);
  k_transpose_w<<<dim3(32, 32, 3), dim3(32, 8), 0, stream>>>(Wq, Wk, Wv, wt);
  k_qkv_gemm<<<dim3(MTOT / 128, DIM / 128, 3), dim3(256), 0, stream>>>(xb, wt, qb, kb, vt);
  k_attn<<<dim3(BATCH, 64), dim3(1024), 0, stream>>>(qb, kb, vt, out);
}

// Round 4
// 1281.682 us; speedup vs baseline: 1.0024x; 1.0024x over previous
//
#include <hip/hip_runtime.h>

// CausalAttention: B=4, S=4096, D_IN=D_OUT=1024, fp32 in/out, bf16 MFMA compute.
//
// R4: identical structure to R3, ONE change: __launch_bounds__(1024, 4).
// R3 regression root cause: __launch_bounds__(1024) without min-waves let the
// compiler target 8 waves/EU -> 64-VGPR cap -> spilled the ~120-reg live set
// (WRITE_SIZE 1.06 GB of scratch traffic). (1024,4) -> 512/4 = 128 VGPR cap,
// matching the designed live set; 16 waves = 1 block/CU.
//
// Fragment layouts (HW-verified, learn_hip m89/m91/m120):
//   A[m = lane&15][k = (lane>>4)*8 + j]
//   B[k = (lane>>4)*8 + j][n = lane&15]
//   D[row = (lane>>4)*4 + r][col = lane&15]

typedef __attribute__((ext_vector_type(8))) short bh8;
typedef __attribute__((ext_vector_type(4))) float f32x4;
typedef __attribute__((ext_vector_type(4))) unsigned int u32x4;

#define BATCH 4
#define SEQ   4096
#define DIM   1024
#define MTOT  (BATCH * SEQ)   // 16384

__device__ __forceinline__ unsigned short f2bf(float f) {
  union { float f; unsigned int u; } v; v.f = f;
  return (unsigned short)((v.u + 0x7FFFu + ((v.u >> 16) & 1u)) >> 16);  // RNE
}

// ---------------- kernel 1: x fp32 -> bf16 ----------------
__global__ __launch_bounds__(256)
void k_convert_x(const float* __restrict__ x, unsigned short* __restrict__ xb) {
  size_t idx = ((size_t)blockIdx.x * 256 + threadIdx.x) * 8;
  f32x4 v0 = *(const f32x4*)(x + idx);
  f32x4 v1 = *(const f32x4*)(x + idx + 4);
  u32x4 pk;
  pk[0] = (unsigned)f2bf(v0[0]) | ((unsigned)f2bf(v0[1]) << 16);
  pk[1] = (unsigned)f2bf(v0[2]) | ((unsigned)f2bf(v0[3]) << 16);
  pk[2] = (unsigned)f2bf(v1[0]) | ((unsigned)f2bf(v1[1]) << 16);
  pk[3] = (unsigned)f2bf(v1[2]) | ((unsigned)f2bf(v1[3]) << 16);
  *(u32x4*)(xb + idx) = pk;
}

// ---------------- kernel 2: W[k][n] fp32 -> Wt[n][k] bf16 (x3) ----------------
__global__ __launch_bounds__(256)
void k_transpose_w(const float* __restrict__ Wq, const float* __restrict__ Wk,
                   const float* __restrict__ Wv, unsigned short* __restrict__ wt) {
  __shared__ float tile[32][33];
  const int z = blockIdx.z;
  const float* W = (z == 0) ? Wq : ((z == 1) ? Wk : Wv);
  unsigned short* out = wt + (size_t)z * DIM * DIM;
  const int tx = threadIdx.x, ty = threadIdx.y;
  const int n = blockIdx.x * 32 + tx;
  const int k = blockIdx.y * 32 + ty;
#pragma unroll
  for (int i = 0; i < 32; i += 8)
    tile[ty + i][tx] = W[(size_t)(k + i) * DIM + n];
  __syncthreads();
  const int k2 = blockIdx.y * 32 + tx;
  const int n2 = blockIdx.x * 32 + ty;
#pragma unroll
  for (int i = 0; i < 32; i += 8)
    out[(size_t)(n2 + i) * DIM + k2] = f2bf(tile[tx][ty + i]);
}

// ---------------- kernel 3: QKV GEMM ----------------
// C[16384,1024] = xb @ W   (z=0 -> qb, z=1 -> kb, z=2 -> vt transposed [b][d][s])
__global__ __launch_bounds__(256)
void k_qkv_gemm(const unsigned short* __restrict__ xb, const unsigned short* __restrict__ wt,
                unsigned short* __restrict__ qb, unsigned short* __restrict__ kb,
                unsigned short* __restrict__ vt) {
  const int tid = threadIdx.x;
  const int l = tid & 63, w = tid >> 6;
  const int lane16 = l & 15, quad = l >> 4;
  const int wm = w & 1, wn = w >> 1;
  const int m0 = blockIdx.x * 128, n0 = blockIdx.y * 128, z = blockIdx.z;
  const unsigned short* wtz = wt + (size_t)z * DIM * DIM;

  __shared__ unsigned short As[128][40];
  __shared__ unsigned short Bs[128][40];

  f32x4 acc[4][4];
#pragma unroll
  for (int i = 0; i < 4; ++i)
#pragma unroll
    for (int j = 0; j < 4; ++j) acc[i][j] = (f32x4){0.f, 0.f, 0.f, 0.f};

  for (int k0 = 0; k0 < DIM; k0 += 32) {
#pragma unroll
    for (int i = 0; i < 2; ++i) {
      int c = tid + i * 256;
      int row = c >> 2, cc = (c & 3) * 8;
      *(bh8*)&As[row][cc] = *(const bh8*)(xb  + (size_t)(m0 + row) * DIM + k0 + cc);
      *(bh8*)&Bs[row][cc] = *(const bh8*)(wtz + (size_t)(n0 + row) * DIM + k0 + cc);
    }
    __syncthreads();
    bh8 a[4], b[4];
#pragma unroll
    for (int mt = 0; mt < 4; ++mt) a[mt] = *(const bh8*)&As[wm * 64 + mt * 16 + lane16][quad * 8];
#pragma unroll
    for (int nt = 0; nt < 4; ++nt) b[nt] = *(const bh8*)&Bs[wn * 64 + nt * 16 + lane16][quad * 8];
#pragma unroll
    for (int mt = 0; mt < 4; ++mt)
#pragma unroll
      for (int nt = 0; nt < 4; ++nt)
        acc[mt][nt] = __builtin_amdgcn_mfma_f32_16x16x32_bf16(a[mt], b[nt], acc[mt][nt], 0, 0, 0);
    __syncthreads();
  }

  if (z < 2) {
    unsigned short* outp = (z == 0) ? qb : kb;
#pragma unroll
    for (int mt = 0; mt < 4; ++mt)
#pragma unroll
      for (int nt = 0; nt < 4; ++nt) {
        int row = m0 + wm * 64 + mt * 16 + quad * 4;
        int col = n0 + wn * 64 + nt * 16 + lane16;
#pragma unroll
        for (int r = 0; r < 4; ++r)
          outp[(size_t)(row + r) * DIM + col] = f2bf(acc[mt][nt][r]);
      }
  } else {
#pragma unroll
    for (int mt = 0; mt < 4; ++mt)
#pragma unroll
      for (int nt = 0; nt < 4; ++nt) {
        int m = m0 + wm * 64 + mt * 16 + quad * 4;
        int bb = m >> 12, s = m & (SEQ - 1);
        int col = n0 + wn * 64 + nt * 16 + lane16;
        unsigned long long pk =
            (unsigned long long)f2bf(acc[mt][nt][0]) |
            ((unsigned long long)f2bf(acc[mt][nt][1]) << 16) |
            ((unsigned long long)f2bf(acc[mt][nt][2]) << 32) |
            ((unsigned long long)f2bf(acc[mt][nt][3]) << 48);
        *(unsigned long long*)(vt + (size_t)bb * DIM * SEQ + (size_t)col * SEQ + s) = pk;
      }
  }
}

// ---------------- kernel 4: causal flash attention (v4 = v3 + reg budget) ----------------
// 1024 threads = 16 waves, 1 block/CU. __launch_bounds__(1024,4): 4 waves/EU
// -> 128-VGPR cap, matching the ~120-reg live set (no spills).
// QK: wave w -> D-slice [w*64,+64), TK=32, writes its own Pp copy (no atomics).
// softmax: 1 cell/thread, 16-copy sum, 32-lane shuffle reduce.
// PV: wave w -> output cols [w*64,+64), o = 2x4 f32x4.
__global__ __launch_bounds__(1024, 4)
void k_attn(const unsigned short* __restrict__ qb, const unsigned short* __restrict__ kb,
            const unsigned short* __restrict__ vt, float* __restrict__ out) {
  const int tid = threadIdx.x;
  const int w = tid >> 6;          // 0..15
  const int l = tid & 63;
  const int lane16 = l & 15, quad = l >> 4;
  const int batch = blockIdx.x;    // fast dim -> XCD affinity per batch
  const int pid = blockIdx.y;      // 0..63
  const int sr = tid >> 5;         // softmax row 0..31
  const int sc = tid & 31;         // softmax col 0..31

  __shared__ float Pp[16][32][36];          // 73.7 KB partial scores (16 copies)
  __shared__ unsigned short Psh[32][36];    // P bf16 for PV A-frags
  __shared__ float row_m[32], row_l[32], row_alpha[32];
  float* Oe = (float*)Pp;                   // epilogue alias (Pp dead then)

  const size_t bbase = (size_t)batch * SEQ;
  const unsigned short* vtb = vt + (size_t)batch * DIM * SEQ;
  const float cexp = 0.04508422002778f;     // log2(e)/sqrt(1024)

  for (int half = 0; half < 2; ++half) {
    const int t = half ? (127 - pid) : pid;
    const int q0 = t * 32;
    const int nk = t + 1;                   // TK=32 iterations

    // Q fragments: this wave's 64-dim slice, 2 row-blocks (16 regs, held)
    bh8 qf[2][2];
#pragma unroll
    for (int mt = 0; mt < 2; ++mt)
#pragma unroll
      for (int c = 0; c < 2; ++c)
        qf[mt][c] = *(const bh8*)(qb + (bbase + q0 + mt * 16 + lane16) * DIM +
                                  w * 64 + c * 32 + quad * 8);

    f32x4 o[2][4];
#pragma unroll
    for (int mt = 0; mt < 2; ++mt)
#pragma unroll
      for (int nt = 0; nt < 4; ++nt) o[mt][nt] = (f32x4){0.f, 0.f, 0.f, 0.f};

    bh8 kfA[2][2], kfB[2][2], vf[4], pf[2];
    // K(0)
#pragma unroll
    for (int kt = 0; kt < 2; ++kt)
#pragma unroll
      for (int c = 0; c < 2; ++c)
        kfA[kt][c] = *(const bh8*)(kb + (bbase + kt * 16 + lane16) * DIM +
                                   w * 64 + c * 32 + quad * 8);

    for (int it = 0; it < nk; ++it) {
      const int k0 = it * 32;

      // issue K(it+1) at span top: full span of latency cover before use
      if (it + 1 < nk) {
#pragma unroll
        for (int kt = 0; kt < 2; ++kt)
#pragma unroll
          for (int c = 0; c < 2; ++c)
            kfB[kt][c] = *(const bh8*)(kb + (bbase + k0 + 32 + kt * 16 + lane16) * DIM +
                                       w * 64 + c * 32 + quad * 8);
      }

      // PV(it-1): rescale by alpha, then P @ V
      if (it > 0) {
        f32x4 al0, al1;
#pragma unroll
        for (int r = 0; r < 4; ++r) {
          al0[r] = row_alpha[quad * 4 + r];
          al1[r] = row_alpha[16 + quad * 4 + r];
        }
#pragma unroll
        for (int nt = 0; nt < 4; ++nt) { o[0][nt] *= al0; o[1][nt] *= al1; }
#pragma unroll
        for (int nt = 0; nt < 4; ++nt)
#pragma unroll
          for (int mt = 0; mt < 2; ++mt)
            o[mt][nt] = __builtin_amdgcn_mfma_f32_16x16x32_bf16(pf[mt], vf[nt], o[mt][nt], 0, 0, 0);
      }

      // QK(it): 32x32 scores over this wave's 64 dims -> own Pp copy
#pragma unroll
      for (int mt = 0; mt < 2; ++mt)
#pragma unroll
        for (int kt = 0; kt < 2; ++kt) {
          f32x4 s = (f32x4){0.f, 0.f, 0.f, 0.f};
          s = __builtin_amdgcn_mfma_f32_16x16x32_bf16(qf[mt][0], kfA[kt][0], s, 0, 0, 0);
          s = __builtin_amdgcn_mfma_f32_16x16x32_bf16(qf[mt][1], kfA[kt][1], s, 0, 0, 0);
          int row = mt * 16 + quad * 4;
          int col = kt * 16 + lane16;
#pragma unroll
          for (int r = 0; r < 4; ++r)
            Pp[w][row + r][col] = s[r];
        }
      __syncthreads();  // barrier1: partials visible

      // issue V(it): softmax span of cover; used in next span's PV
#pragma unroll
      for (int nt = 0; nt < 4; ++nt)
        vf[nt] = *(const bh8*)(vtb + (size_t)(w * 64 + nt * 16 + lane16) * SEQ +
                               k0 + quad * 8);

      // softmax: one cell per thread
      {
        float sv = Pp[0][sr][sc];
#pragma unroll
        for (int k = 1; k < 16; ++k) sv += Pp[k][sr][sc];
        if (k0 + sc > q0 + sr) sv = -3.0e38f;
        float mx = sv;
#pragma unroll
        for (int off = 1; off < 32; off <<= 1)
          mx = fmaxf(mx, __shfl_xor(mx, off));
        float mold = it ? row_m[sr] : -3.0e38f;
        float mnew = fmaxf(mold, mx);
        float p = __builtin_amdgcn_exp2f((sv - mnew) * cexp);
        float sum = p;
#pragma unroll
        for (int off = 1; off < 32; off <<= 1)
          sum += __shfl_xor(sum, off);
        float alpha = __builtin_amdgcn_exp2f((mold - mnew) * cexp);
        Psh[sr][sc] = f2bf(p);
        if (sc == 0) {
          row_m[sr] = mnew;
          row_l[sr] = alpha * (it ? row_l[sr] : 0.f) + sum;
          row_alpha[sr] = alpha;
        }
      }
      __syncthreads();  // barrier2: Psh / row state visible

      // P fragments for PV (A-layout)
      pf[0] = *(const bh8*)&Psh[lane16][quad * 8];
      pf[1] = *(const bh8*)&Psh[16 + lane16][quad * 8];

      // rotate K double-buffer
      if (it + 1 < nk) {
#pragma unroll
        for (int kt = 0; kt < 2; ++kt)
#pragma unroll
          for (int c = 0; c < 2; ++c) kfA[kt][c] = kfB[kt][c];
      }
    }

    // tail PV(nk-1)
    {
      f32x4 al0, al1;
#pragma unroll
      for (int r = 0; r < 4; ++r) {
        al0[r] = row_alpha[quad * 4 + r];
        al1[r] = row_alpha[16 + quad * 4 + r];
      }
#pragma unroll
      for (int nt = 0; nt < 4; ++nt) { o[0][nt] *= al0; o[1][nt] *= al1; }
#pragma unroll
      for (int nt = 0; nt < 4; ++nt)
#pragma unroll
        for (int mt = 0; mt < 2; ++mt)
          o[mt][nt] = __builtin_amdgcn_mfma_f32_16x16x32_bf16(pf[mt], vf[nt], o[mt][nt], 0, 0, 0);
    }

    // epilogue: divide by l, LDS-transpose (wave-local, reuses dead Pp),
    // then 128B-contiguous fp32 stores.
    {
      float* Ow = Oe + w * 1040;  // 16 rows x 65 floats per wave
#pragma unroll
      for (int mt = 0; mt < 2; ++mt) {
        float il[4];
#pragma unroll
        for (int r = 0; r < 4; ++r) il[r] = 1.0f / row_l[mt * 16 + quad * 4 + r];
#pragma unroll
        for (int nt = 0; nt < 4; ++nt)
#pragma unroll
          for (int r = 0; r < 4; ++r)
            Ow[(quad * 4 + r) * 65 + nt * 16 + lane16] = o[mt][nt][r] * il[r];
        // same-wave LDS RAW: compiler inserts lgkmcnt wait
        int row8 = l >> 3, c8 = l & 7;
#pragma unroll
        for (int set = 0; set < 2; ++set)
#pragma unroll
          for (int rep = 0; rep < 2; ++rep) {
            f32x4 v = *(const f32x4*)&Ow[(set * 8 + row8) * 65 + c8 * 4 + rep * 32];
            *(f32x4*)(out + (bbase + q0 + mt * 16 + set * 8 + row8) * DIM +
                      w * 64 + c8 * 4 + rep * 32) = v;
          }
      }
    }
    __syncthreads();  // Pp/row state reused by next tile
  }
}

// ---------------- launch ----------------
extern "C" void kernel_launch(void* const* d_in, const int* in_sizes, int n_in,
                              void* d_out, int out_size, void* d_ws, size_t ws_size,
                              hipStream_t stream) {
  const float* x  = (const float*)d_in[0];
  const float* Wq = (const float*)d_in[1];
  const float* Wk = (const float*)d_in[2];
  const float* Wv = (const float*)d_in[3];
  float* out = (float*)d_out;

  char* ws = (char*)d_ws;
  const size_t XB_BYTES = (size_t)MTOT * DIM * 2;        // 32 MB
  const size_t WT_BYTES = (size_t)3 * DIM * DIM * 2;     // 6 MB
  unsigned short* xb = (unsigned short*)(ws);
  unsigned short* wt = (unsigned short*)(ws + XB_BYTES);
  unsigned short* qb = (unsigned short*)(ws + XB_BYTES + WT_BYTES);
  unsigned short* kb = qb + (size_t)MTOT * DIM;
  unsigned short* vt = kb + (size_t)MTOT * DIM;

  k_convert_x<<<dim3((MTOT * DIM) / (256 * 8)), dim3(256), 0, stream>>>(x, xb);
  k_transpose_w<<<dim3(32, 32, 3), dim3(32, 8), 0, stream>>>(Wq, Wk, Wv, wt);
  k_qkv_gemm<<<dim3(MTOT / 128, DIM / 128, 3), dim3(256), 0, stream>>>(xb, wt, qb, kb, vt);
  k_attn<<<dim3(BATCH, 64), dim3(1024), 0, stream>>>(qb, kb, vt, out);
}